// Round 7
// baseline (3267.574 us; speedup 1.0000x reference)
//
#include <hip/hip_runtime.h>

#define N_USER 100000
#define N_ITEM 100000
#define N_NODES 200000
#define NNZ 6400000
#define EMB 64
#define BATCH 1024

typedef __attribute__((ext_vector_type(8))) short bf16x8;   // 8 bf16 = 4 VGPRs
typedef __attribute__((ext_vector_type(4))) float f32x4;    // MFMA 16x16 acc

// ---------------------------------------------------------------------------
// Workspace layout:
//   ego_h   : N_NODES*EMB bf16  (25.6 MB) bf16 state (dense A-operand, gather_norm)
//   side_h  : N_NODES*EMB bf16  (25.6 MB) spmm output
//   ego_q   : N_NODES*EMB u8    (12.8 MB) offset-binary u8 state (spmm gather)
//   gmax    : 4 uint                      per-layer global absmax (f32 bits)
//   row_ptr : padded ints                 CSR row starts (adj_row is sorted)
//   wfrag   : 6*8*64*8 bf16     (48 KB)   weights pre-packed into B-fragments
// Global-scale u8: spmm needs NO per-nnz scale traffic (the R5 mistake):
//   y_d = g * (sum val*u_d - 128 * sum val),  g = gmax/127 (wave-uniform).
// ---------------------------------------------------------------------------

// f32 -> bf16 (RNE), raw ushort bits
__device__ __forceinline__ unsigned short f2bf(float f) {
    unsigned int b = __builtin_bit_cast(unsigned int, f);
    b += 0x7FFFu + ((b >> 16) & 1u);
    return (unsigned short)(b >> 16);
}
__device__ __forceinline__ float bf2f(unsigned short u) {
    return __builtin_bit_cast(float, (unsigned int)u << 16);
}
__device__ __forceinline__ unsigned int pack2(float lo, float hi) {
    return ((unsigned int)f2bf(hi) << 16) | f2bf(lo);
}
// offset-binary u8 quant: u = rint(v*inv)+128, inv = 127/gmax
__device__ __forceinline__ unsigned int quant_u8(float v, float inv) {
    return (unsigned int)((int)__builtin_rintf(v * inv) + 128);
}

// elementwise product of two bf16 fragments (A-layouts align), f32 math
__device__ __forceinline__ bf16x8 mul_bf(bf16x8 a, bf16x8 b) {
    bf16x8 r;
#pragma unroll
    for (int j = 0; j < 8; ++j) {
        float f = bf2f((unsigned short)a[j]) * bf2f((unsigned short)b[j]);
        r[j] = (short)f2bf(f);
    }
    return r;
}

__global__ void init_gmax(unsigned int* __restrict__ gmax) {
    if (threadIdx.x < 4) gmax[threadIdx.x] = 0u;
}

// row_ptr[r] = lower_bound(adj_row, r); every r in [0, N_NODES] written once.
__global__ void build_row_ptr(const int* __restrict__ row, int* __restrict__ row_ptr) {
    int i = blockIdx.x * blockDim.x + threadIdx.x;
    if (i >= NNZ) return;
    int b = row[i];
    int a = (i == 0) ? -1 : row[i - 1];
    for (int r = a + 1; r <= b; ++r) row_ptr[r] = i;
    if (i == NNZ - 1) {
        for (int r = b + 1; r <= N_NODES; ++r) row_ptr[r] = NNZ;
    }
}

// wave per node row: bf16 state + per-wave absmax -> atomicMax(gmax[0])
__global__ __launch_bounds__(256) void concat_ego(
        const float* __restrict__ ue, const float* __restrict__ ie,
        unsigned short* __restrict__ ego_h, unsigned int* __restrict__ gmax) {
    int wave = (blockIdx.x * blockDim.x + threadIdx.x) >> 6;
    int lane = threadIdx.x & 63;
    if (wave >= N_NODES) return;
    float v = (wave < N_USER) ? ue[(size_t)wave * EMB + lane]
                              : ie[(size_t)(wave - N_USER) * EMB + lane];
    ego_h[(size_t)wave * EMB + lane] = f2bf(v);
    float m = fabsf(v);
#pragma unroll
    for (int off = 1; off < 64; off <<= 1) m = fmaxf(m, __shfl_xor(m, off));
    if (lane == 0)
        atomicMax(gmax, __builtin_bit_cast(unsigned int, m));  // m>=0: bits monotone
}

// streaming quant pass: ego_q = u8(ego_h) with global scale gmax[layer]
__global__ __launch_bounds__(256) void quant_pass(
        const unsigned short* __restrict__ ego_h, const unsigned int* __restrict__ gmax,
        int layer, unsigned char* __restrict__ ego_q) {
    int i = blockIdx.x * blockDim.x + threadIdx.x;   // 8-elem group index
    const int tot8 = N_NODES * EMB / 8;
    if (i >= tot8) return;
    float gm = __builtin_bit_cast(float, gmax[layer]);
    float inv = gm > 0.f ? 127.f / gm : 0.f;
    bf16x8 h = ((const bf16x8*)ego_h)[i];
    uint2 o;
    o.x = 0; o.y = 0;
#pragma unroll
    for (int j = 0; j < 4; ++j)
        o.x |= quant_u8(bf2f((unsigned short)h[j]), inv) << (8 * j);
#pragma unroll
    for (int j = 0; j < 4; ++j)
        o.y |= quant_u8(bf2f((unsigned short)h[4 + j]), inv) << (8 * j);
    ((uint2*)ego_q)[i] = o;
}

// pack the 6 64x64 f32 weight matrices into MFMA B-fragment layout (bf16).
__global__ void prep_wfrags(const float* __restrict__ W0, const float* __restrict__ W1,
                            const float* __restrict__ W2, const float* __restrict__ W3,
                            const float* __restrict__ W4, const float* __restrict__ W5,
                            unsigned short* __restrict__ wfrag) {
    int m = blockIdx.x >> 3;
    int t = (blockIdx.x >> 1) & 3, c = blockIdx.x & 1;
    const float* W = m == 0 ? W0 : m == 1 ? W1 : m == 2 ? W2 : m == 3 ? W3 : m == 4 ? W4 : W5;
    int l = threadIdx.x, quad = l >> 4, n = l & 15;
    unsigned short* dst = wfrag + ((size_t)blockIdx.x * 64 + l) * 8;
#pragma unroll
    for (int j = 0; j < 8; ++j)
        dst[j] = f2bf(W[(c * 32 + quad * 8 + j) * 64 + t * 16 + n]);
}

__device__ __forceinline__ int batch_node(const int* users, const int* pos,
                                          const int* neg, int b) {
    int t = b >> 10, idx = b & 1023;
    if (t == 0) return users[idx];
    if (t == 1) return N_USER + pos[idx];
    return N_USER + neg[idx];
}

// layer-0 output columns: exact f32 from the original input embeddings
__global__ void gather_layer0(const int* __restrict__ users, const int* __restrict__ pos,
                              const int* __restrict__ neg, const float* __restrict__ ue,
                              const float* __restrict__ ie, float* __restrict__ out) {
    int b = blockIdx.x;
    int node = batch_node(users, pos, neg, b);
    float v = (node < N_USER) ? ue[(size_t)node * EMB + threadIdx.x]
                              : ie[(size_t)(node - N_USER) * EMB + threadIdx.x];
    out[(size_t)b * 256 + threadIdx.x] = v;
}

// CSR SpMM, u8 quarter-wave gather, GLOBAL dequant scale (zero per-nnz scale
// traffic). Wave = 1 row; 16 lanes x dword (4 u8 dims) cover the 64B row ->
// one gather (one 64B sector) serves 4 nnz. (col,val) staged coalesced per
// 32-chunk; per-quarter broadcast via ds_bpermute.
__global__ __launch_bounds__(256) void spmm_csr(
        const int* __restrict__ row_ptr, const int* __restrict__ col,
        const float* __restrict__ val, const unsigned char* __restrict__ xq,
        const unsigned int* __restrict__ gmax, int layer,
        unsigned short* __restrict__ yh) {
    int wave = (blockIdx.x * blockDim.x + threadIdx.x) >> 6;
    int lane = threadIdx.x & 63;
    if (wave >= N_NODES) return;
    int q = lane >> 4, p = lane & 15;
    int q4 = q << 2;
    unsigned pb = (unsigned)p * 4u;                 // byte offset in row
    int j0 = row_ptr[wave], j1 = row_ptr[wave + 1];
    float a0 = 0.f, a1 = 0.f, a2 = 0.f, a3 = 0.f, cs = 0.f;
    for (int j = j0; j < j1; j += 32) {
        int jl = j + (lane & 31);                   // lanes 32..63 duplicate 0..31
        bool ok = jl < j1;
        int   cc = ok ? __builtin_nontemporal_load(col + jl) : 0;
        float vr = ok ? __builtin_nontemporal_load(val + jl) : 0.f;
        int   vvi = __builtin_bit_cast(int, vr);
        int n = j1 - j;
#pragma unroll
        for (int g = 0; g < 4; ++g) {
            if (g * 8 >= n) break;                  // wave-uniform exit
#pragma unroll
            for (int s = 0; s < 2; ++s) {
                const int t = g * 8 + s * 4;        // this step: nnz t..t+3
                int   ct  = __builtin_amdgcn_ds_bpermute(q4 + t * 4, cc);
                float vts = __builtin_bit_cast(float,
                             __builtin_amdgcn_ds_bpermute(q4 + t * 4, vvi));
                unsigned idx = (unsigned)ct * 64u + pb;
                unsigned d = *(const unsigned*)(xq + idx);
                a0 = fmaf(vts, (float)(d & 0xffu), a0);
                a1 = fmaf(vts, (float)((d >> 8) & 0xffu), a1);
                a2 = fmaf(vts, (float)((d >> 16) & 0xffu), a2);
                a3 = fmaf(vts, (float)(d >> 24), a3);
                cs += vts;
            }
        }
    }
    // combine the 4 quarter-partials (lane p keeps dims 4p..4p+3)
    a0 += __shfl_xor(a0, 16); a0 += __shfl_xor(a0, 32);
    a1 += __shfl_xor(a1, 16); a1 += __shfl_xor(a1, 32);
    a2 += __shfl_xor(a2, 16); a2 += __shfl_xor(a2, 32);
    a3 += __shfl_xor(a3, 16); a3 += __shfl_xor(a3, 32);
    cs += __shfl_xor(cs, 16); cs += __shfl_xor(cs, 32);
    if (q == 0) {
        float gsc = __builtin_bit_cast(float, gmax[layer]) * (1.f / 127.f);
        float c128 = 128.f * cs;
        uint2 o;
        o.x = pack2(gsc * (a0 - c128), gsc * (a1 - c128));
        o.y = pack2(gsc * (a2 - c128), gsc * (a3 - c128));
        ((uint2*)(yh + (size_t)wave * EMB))[p] = o;   // 16 lanes x 8B = full row
    }
}

// MFMA dense layer: ego_h <- bf16(leaky_relu(side@Wgc+bgc+(ego*side)@Wbi+bbi)).
// Light epilogue: bf16 stores + per-wave absmax -> one atomicMax(gmax[k+1]).
__global__ __launch_bounds__(256) void dense_mfma(
        const unsigned short* __restrict__ side_h,
        unsigned short* __restrict__ ego_h,
        const unsigned short* __restrict__ wf,   // this layer: [m][t][c][lane][8]
        const float* __restrict__ bgc, const float* __restrict__ bbi,
        unsigned int* __restrict__ gmax_out) {
    int wave = threadIdx.x >> 6;
    int lane = threadIdx.x & 63;
    int quad = lane >> 4, n = lane & 15;
    int r0 = blockIdx.x * 64 + wave * 16;

    bf16x8 bfrag[2][4][2];
#pragma unroll
    for (int m = 0; m < 2; ++m)
#pragma unroll
        for (int t = 0; t < 4; ++t)
#pragma unroll
            for (int c = 0; c < 2; ++c)
                bfrag[m][t][c] = *(const bf16x8*)(wf + ((size_t)((m * 4 + t) * 2 + c) * 64 + lane) * 8);

    f32x4 acc[4];
#pragma unroll
    for (int t = 0; t < 4; ++t) {
        float bs = bgc[t * 16 + n] + bbi[t * 16 + n];
        acc[t] = (f32x4){bs, bs, bs, bs};
    }

    size_t abase = (size_t)(r0 + n) * EMB + quad * 8;
    bf16x8 as0 = *(const bf16x8*)(side_h + abase);
    bf16x8 as1 = *(const bf16x8*)(side_h + abase + 32);
    bf16x8 ae0 = *(const bf16x8*)(ego_h + abase);
    bf16x8 ae1 = *(const bf16x8*)(ego_h + abase + 32);
    bf16x8 ap0 = mul_bf(ae0, as0);
    bf16x8 ap1 = mul_bf(ae1, as1);

#pragma unroll
    for (int t = 0; t < 4; ++t) {
        acc[t] = __builtin_amdgcn_mfma_f32_16x16x32_bf16(as0, bfrag[0][t][0], acc[t], 0, 0, 0);
        acc[t] = __builtin_amdgcn_mfma_f32_16x16x32_bf16(as1, bfrag[0][t][1], acc[t], 0, 0, 0);
        acc[t] = __builtin_amdgcn_mfma_f32_16x16x32_bf16(ap0, bfrag[1][t][0], acc[t], 0, 0, 0);
        acc[t] = __builtin_amdgcn_mfma_f32_16x16x32_bf16(ap1, bfrag[1][t][1], acc[t], 0, 0, 0);
    }

    // epilogue: C/D layout col=lane&15, row=quad*4+reg (m89-verified)
    float m = 0.f;
#pragma unroll
    for (int t = 0; t < 4; ++t)
#pragma unroll
        for (int i = 0; i < 4; ++i) {
            float v = acc[t][i];
            float o = v > 0.f ? v : 0.2f * v;
            m = fmaxf(m, fabsf(o));
            ego_h[(size_t)(r0 + quad * 4 + i) * EMB + t * 16 + n] = f2bf(o);
        }
#pragma unroll
    for (int off = 1; off < 64; off <<= 1) m = fmaxf(m, __shfl_xor(m, off));
    if (lane == 0)
        atomicMax(gmax_out, __builtin_bit_cast(unsigned int, m));
}

// gather batch rows of ego_h (bf16), L2-normalize, write out cols [64*layer,...)
__global__ void gather_norm(const int* __restrict__ users, const int* __restrict__ pos,
                            const int* __restrict__ neg,
                            const unsigned short* __restrict__ ego_h,
                            float* __restrict__ out, int layer) {
    int b = blockIdx.x;
    int lane = threadIdx.x;
    int node = batch_node(users, pos, neg, b);
    float v = bf2f(ego_h[(size_t)node * EMB + lane]);
    float s = v * v;
#pragma unroll
    for (int off = 32; off > 0; off >>= 1) s += __shfl_xor(s, off);
    float n = fmaxf(sqrtf(s), 1e-12f);
    out[(size_t)b * 256 + layer * EMB + lane] = v / n;
}

extern "C" void kernel_launch(void* const* d_in, const int* in_sizes, int n_in,
                              void* d_out, int out_size, void* d_ws, size_t ws_size,
                              hipStream_t stream) {
    const int*   users    = (const int*)d_in[0];
    const int*   pos      = (const int*)d_in[1];
    const int*   neg      = (const int*)d_in[2];
    const int*   adj_row  = (const int*)d_in[3];
    const int*   adj_col  = (const int*)d_in[4];
    const float* adj_val  = (const float*)d_in[5];
    const float* user_emb = (const float*)d_in[6];
    const float* item_emb = (const float*)d_in[7];
    // d_in[8..19]: W_gc_0, b_gc_0, W_bi_0, b_bi_0, W_gc_1, ... (4 per layer)

    unsigned short* ego_h   = (unsigned short*)d_ws;
    unsigned short* side_h  = ego_h + (size_t)N_NODES * EMB;
    unsigned char*  ego_q   = (unsigned char*)(side_h + (size_t)N_NODES * EMB);
    unsigned int*   gmax    = (unsigned int*)(ego_q + (size_t)N_NODES * EMB);
    int*            row_ptr = (int*)(gmax + 4);
    unsigned short* wfrag   = (unsigned short*)(row_ptr + 200704 + 28);  // 16B-aligned
    float*          out     = (float*)d_out;

    init_gmax<<<1, 64, 0, stream>>>(gmax);
    build_row_ptr<<<(NNZ + 255) / 256, 256, 0, stream>>>(adj_row, row_ptr);
    concat_ego<<<N_NODES / 4, 256, 0, stream>>>(user_emb, item_emb, ego_h, gmax);
    prep_wfrags<<<48, 64, 0, stream>>>((const float*)d_in[8], (const float*)d_in[10],
                                       (const float*)d_in[12], (const float*)d_in[14],
                                       (const float*)d_in[16], (const float*)d_in[18], wfrag);
    gather_layer0<<<3 * BATCH, 64, 0, stream>>>(users, pos, neg, user_emb, item_emb, out);
    quant_pass<<<(N_NODES * EMB / 8 + 255) / 256, 256, 0, stream>>>(ego_h, gmax, 0, ego_q);

    for (int k = 0; k < 3; ++k) {
        const float* bgc = (const float*)d_in[9 + 4 * k];
        const float* bbi = (const float*)d_in[11 + 4 * k];
        spmm_csr<<<N_NODES / 4, 256, 0, stream>>>(row_ptr, adj_col, adj_val, ego_q, gmax, k, side_h);
        dense_mfma<<<N_NODES / 64, 256, 0, stream>>>(side_h, ego_h,
                                                     wfrag + (size_t)k * 2 * 8 * 64 * 8,
                                                     bgc, bbi, gmax + k + 1);
        if (k < 2)
            quant_pass<<<(N_NODES * EMB / 8 + 255) / 256, 256, 0, stream>>>(ego_h, gmax, k + 1, ego_q);
        gather_norm<<<3 * BATCH, 64, 0, stream>>>(users, pos, neg, ego_h, out, k + 1);
    }
}

// Round 8
// 650.097 us; speedup vs baseline: 5.0263x; 5.0263x over previous
//
#include <hip/hip_runtime.h>

#define N_USER 100000
#define N_ITEM 100000
#define N_NODES 200000
#define NNZ 6400000
#define EMB 64
#define BATCH 1024

typedef __attribute__((ext_vector_type(8))) short bf16x8;   // 8 bf16 = 4 VGPRs
typedef __attribute__((ext_vector_type(4))) float f32x4;    // MFMA 16x16 acc

// ---------------------------------------------------------------------------
// Workspace layout:
//   ego_h   : N_NODES*EMB bf16  (25.6 MB) bf16 state (dense A-operand, gather_norm)
//   side_h  : N_NODES*EMB bf16  (25.6 MB) spmm output
//   ego_q   : N_NODES*EMB u8    (12.8 MB) offset-binary u8 state (spmm gather)
//   gmax    : 4 floats                    per-layer global absmax
//   partial : 50000 floats                block-level max partials (no atomics!)
//   row_ptr : padded ints                 CSR row starts (adj_row is sorted)
//   wfrag   : 6*8*64*8 bf16     (48 KB)   weights pre-packed into B-fragments
// Global-scale u8 spmm: y_d = g*(sum val*u_d - 128*sum val), g wave-uniform.
// R6 lesson: same-address atomicMax from 200k waves serialized at ~11ns each
// (2271 us). Max is now two-stage: block LDS reduce -> partial[], then one
// small reduce_max kernel. Zero global atomics.
// ---------------------------------------------------------------------------

// f32 -> bf16 (RNE), raw ushort bits
__device__ __forceinline__ unsigned short f2bf(float f) {
    unsigned int b = __builtin_bit_cast(unsigned int, f);
    b += 0x7FFFu + ((b >> 16) & 1u);
    return (unsigned short)(b >> 16);
}
__device__ __forceinline__ float bf2f(unsigned short u) {
    return __builtin_bit_cast(float, (unsigned int)u << 16);
}
__device__ __forceinline__ unsigned int pack2(float lo, float hi) {
    return ((unsigned int)f2bf(hi) << 16) | f2bf(lo);
}
// offset-binary u8 quant: u = rint(v*inv)+128, inv = 127/gmax
__device__ __forceinline__ unsigned int quant_u8(float v, float inv) {
    return (unsigned int)((int)__builtin_rintf(v * inv) + 128);
}

// elementwise product of two bf16 fragments (A-layouts align), f32 math
__device__ __forceinline__ bf16x8 mul_bf(bf16x8 a, bf16x8 b) {
    bf16x8 r;
#pragma unroll
    for (int j = 0; j < 8; ++j) {
        float f = bf2f((unsigned short)a[j]) * bf2f((unsigned short)b[j]);
        r[j] = (short)f2bf(f);
    }
    return r;
}

// row_ptr[r] = lower_bound(adj_row, r); every r in [0, N_NODES] written once.
__global__ void build_row_ptr(const int* __restrict__ row, int* __restrict__ row_ptr) {
    int i = blockIdx.x * blockDim.x + threadIdx.x;
    if (i >= NNZ) return;
    int b = row[i];
    int a = (i == 0) ? -1 : row[i - 1];
    for (int r = a + 1; r <= b; ++r) row_ptr[r] = i;
    if (i == NNZ - 1) {
        for (int r = b + 1; r <= N_NODES; ++r) row_ptr[r] = NNZ;
    }
}

// wave per node row: bf16 state; block max -> partial[blockIdx] (no atomics)
__global__ __launch_bounds__(256) void concat_ego(
        const float* __restrict__ ue, const float* __restrict__ ie,
        unsigned short* __restrict__ ego_h, float* __restrict__ partial) {
    __shared__ float smax[4];
    int wave = (blockIdx.x * blockDim.x + threadIdx.x) >> 6;
    int lane = threadIdx.x & 63;
    float m = 0.f;
    if (wave < N_NODES) {
        float v = (wave < N_USER) ? ue[(size_t)wave * EMB + lane]
                                  : ie[(size_t)(wave - N_USER) * EMB + lane];
        ego_h[(size_t)wave * EMB + lane] = f2bf(v);
        m = fabsf(v);
    }
#pragma unroll
    for (int off = 1; off < 64; off <<= 1) m = fmaxf(m, __shfl_xor(m, off));
    if (lane == 0) smax[threadIdx.x >> 6] = m;
    __syncthreads();
    if (threadIdx.x == 0)
        partial[blockIdx.x] = fmaxf(fmaxf(smax[0], smax[1]), fmaxf(smax[2], smax[3]));
}

// fold partial[0..n) into gmax_out[0]; single block of 1024
__global__ __launch_bounds__(1024) void reduce_max(
        const float* __restrict__ partial, int n, float* __restrict__ gmax_out) {
    __shared__ float smax[16];
    float m = 0.f;
    for (int i = threadIdx.x; i < n; i += 1024) m = fmaxf(m, partial[i]);
#pragma unroll
    for (int off = 1; off < 64; off <<= 1) m = fmaxf(m, __shfl_xor(m, off));
    if ((threadIdx.x & 63) == 0) smax[threadIdx.x >> 6] = m;
    __syncthreads();
    if (threadIdx.x < 16) {
        m = smax[threadIdx.x];
#pragma unroll
        for (int off = 1; off < 16; off <<= 1) m = fmaxf(m, __shfl_xor(m, off));
        if (threadIdx.x == 0) gmax_out[0] = m;
    }
}

// streaming quant pass: ego_q = u8(ego_h) with global scale gmax[layer]
__global__ __launch_bounds__(256) void quant_pass(
        const unsigned short* __restrict__ ego_h, const float* __restrict__ gmax,
        int layer, unsigned char* __restrict__ ego_q) {
    int i = blockIdx.x * blockDim.x + threadIdx.x;   // 8-elem group index
    const int tot8 = N_NODES * EMB / 8;
    if (i >= tot8) return;
    float gm = gmax[layer];
    float inv = gm > 0.f ? 127.f / gm : 0.f;
    bf16x8 h = ((const bf16x8*)ego_h)[i];
    uint2 o;
    o.x = 0; o.y = 0;
#pragma unroll
    for (int j = 0; j < 4; ++j)
        o.x |= quant_u8(bf2f((unsigned short)h[j]), inv) << (8 * j);
#pragma unroll
    for (int j = 0; j < 4; ++j)
        o.y |= quant_u8(bf2f((unsigned short)h[4 + j]), inv) << (8 * j);
    ((uint2*)ego_q)[i] = o;
}

// pack the 6 64x64 f32 weight matrices into MFMA B-fragment layout (bf16).
__global__ void prep_wfrags(const float* __restrict__ W0, const float* __restrict__ W1,
                            const float* __restrict__ W2, const float* __restrict__ W3,
                            const float* __restrict__ W4, const float* __restrict__ W5,
                            unsigned short* __restrict__ wfrag) {
    int m = blockIdx.x >> 3;
    int t = (blockIdx.x >> 1) & 3, c = blockIdx.x & 1;
    const float* W = m == 0 ? W0 : m == 1 ? W1 : m == 2 ? W2 : m == 3 ? W3 : m == 4 ? W4 : W5;
    int l = threadIdx.x, quad = l >> 4, n = l & 15;
    unsigned short* dst = wfrag + ((size_t)blockIdx.x * 64 + l) * 8;
#pragma unroll
    for (int j = 0; j < 8; ++j)
        dst[j] = f2bf(W[(c * 32 + quad * 8 + j) * 64 + t * 16 + n]);
}

__device__ __forceinline__ int batch_node(const int* users, const int* pos,
                                          const int* neg, int b) {
    int t = b >> 10, idx = b & 1023;
    if (t == 0) return users[idx];
    if (t == 1) return N_USER + pos[idx];
    return N_USER + neg[idx];
}

// layer-0 output columns: exact f32 from the original input embeddings
__global__ void gather_layer0(const int* __restrict__ users, const int* __restrict__ pos,
                              const int* __restrict__ neg, const float* __restrict__ ue,
                              const float* __restrict__ ie, float* __restrict__ out) {
    int b = blockIdx.x;
    int node = batch_node(users, pos, neg, b);
    float v = (node < N_USER) ? ue[(size_t)node * EMB + threadIdx.x]
                              : ie[(size_t)(node - N_USER) * EMB + threadIdx.x];
    out[(size_t)b * 256 + threadIdx.x] = v;
}

// CSR SpMM, u8 quarter-wave gather, GLOBAL dequant scale (zero per-nnz scale
// traffic). Wave = 1 row; 16 lanes x dword (4 u8 dims) cover the 64B row ->
// one gather (one 64B sector) serves 4 nnz. (col,val) staged coalesced per
// 32-chunk; per-quarter broadcast via ds_bpermute.
__global__ __launch_bounds__(256) void spmm_csr(
        const int* __restrict__ row_ptr, const int* __restrict__ col,
        const float* __restrict__ val, const unsigned char* __restrict__ xq,
        const float* __restrict__ gmax, int layer,
        unsigned short* __restrict__ yh) {
    int wave = (blockIdx.x * blockDim.x + threadIdx.x) >> 6;
    int lane = threadIdx.x & 63;
    if (wave >= N_NODES) return;
    int q = lane >> 4, p = lane & 15;
    int q4 = q << 2;
    unsigned pb = (unsigned)p * 4u;                 // byte offset in row
    int j0 = row_ptr[wave], j1 = row_ptr[wave + 1];
    float a0 = 0.f, a1 = 0.f, a2 = 0.f, a3 = 0.f, cs = 0.f;
    for (int j = j0; j < j1; j += 32) {
        int jl = j + (lane & 31);                   // lanes 32..63 duplicate 0..31
        bool ok = jl < j1;
        int   cc = ok ? __builtin_nontemporal_load(col + jl) : 0;
        float vr = ok ? __builtin_nontemporal_load(val + jl) : 0.f;
        int   vvi = __builtin_bit_cast(int, vr);
        int n = j1 - j;
#pragma unroll
        for (int g = 0; g < 4; ++g) {
            if (g * 8 >= n) break;                  // wave-uniform exit
#pragma unroll
            for (int s = 0; s < 2; ++s) {
                const int t = g * 8 + s * 4;        // this step: nnz t..t+3
                int   ct  = __builtin_amdgcn_ds_bpermute(q4 + t * 4, cc);
                float vts = __builtin_bit_cast(float,
                             __builtin_amdgcn_ds_bpermute(q4 + t * 4, vvi));
                unsigned idx = (unsigned)ct * 64u + pb;
                unsigned d = *(const unsigned*)(xq + idx);
                a0 = fmaf(vts, (float)(d & 0xffu), a0);
                a1 = fmaf(vts, (float)((d >> 8) & 0xffu), a1);
                a2 = fmaf(vts, (float)((d >> 16) & 0xffu), a2);
                a3 = fmaf(vts, (float)(d >> 24), a3);
                cs += vts;
            }
        }
    }
    // combine the 4 quarter-partials (lane p keeps dims 4p..4p+3)
    a0 += __shfl_xor(a0, 16); a0 += __shfl_xor(a0, 32);
    a1 += __shfl_xor(a1, 16); a1 += __shfl_xor(a1, 32);
    a2 += __shfl_xor(a2, 16); a2 += __shfl_xor(a2, 32);
    a3 += __shfl_xor(a3, 16); a3 += __shfl_xor(a3, 32);
    cs += __shfl_xor(cs, 16); cs += __shfl_xor(cs, 32);
    if (q == 0) {
        float gsc = gmax[layer] * (1.f / 127.f);
        float c128 = 128.f * cs;
        uint2 o;
        o.x = pack2(gsc * (a0 - c128), gsc * (a1 - c128));
        o.y = pack2(gsc * (a2 - c128), gsc * (a3 - c128));
        ((uint2*)(yh + (size_t)wave * EMB))[p] = o;   // 16 lanes x 8B = full row
    }
}

// MFMA dense layer: ego_h <- bf16(leaky_relu(side@Wgc+bgc+(ego*side)@Wbi+bbi)).
// Epilogue: bf16 stores; block max -> partial[blockIdx] (no atomics).
__global__ __launch_bounds__(256) void dense_mfma(
        const unsigned short* __restrict__ side_h,
        unsigned short* __restrict__ ego_h,
        const unsigned short* __restrict__ wf,   // this layer: [m][t][c][lane][8]
        const float* __restrict__ bgc, const float* __restrict__ bbi,
        float* __restrict__ partial) {
    __shared__ float smax[4];
    int wave = threadIdx.x >> 6;
    int lane = threadIdx.x & 63;
    int quad = lane >> 4, n = lane & 15;
    int r0 = blockIdx.x * 64 + wave * 16;

    bf16x8 bfrag[2][4][2];
#pragma unroll
    for (int m = 0; m < 2; ++m)
#pragma unroll
        for (int t = 0; t < 4; ++t)
#pragma unroll
            for (int c = 0; c < 2; ++c)
                bfrag[m][t][c] = *(const bf16x8*)(wf + ((size_t)((m * 4 + t) * 2 + c) * 64 + lane) * 8);

    f32x4 acc[4];
#pragma unroll
    for (int t = 0; t < 4; ++t) {
        float bs = bgc[t * 16 + n] + bbi[t * 16 + n];
        acc[t] = (f32x4){bs, bs, bs, bs};
    }

    size_t abase = (size_t)(r0 + n) * EMB + quad * 8;
    bf16x8 as0 = *(const bf16x8*)(side_h + abase);
    bf16x8 as1 = *(const bf16x8*)(side_h + abase + 32);
    bf16x8 ae0 = *(const bf16x8*)(ego_h + abase);
    bf16x8 ae1 = *(const bf16x8*)(ego_h + abase + 32);
    bf16x8 ap0 = mul_bf(ae0, as0);
    bf16x8 ap1 = mul_bf(ae1, as1);

#pragma unroll
    for (int t = 0; t < 4; ++t) {
        acc[t] = __builtin_amdgcn_mfma_f32_16x16x32_bf16(as0, bfrag[0][t][0], acc[t], 0, 0, 0);
        acc[t] = __builtin_amdgcn_mfma_f32_16x16x32_bf16(as1, bfrag[0][t][1], acc[t], 0, 0, 0);
        acc[t] = __builtin_amdgcn_mfma_f32_16x16x32_bf16(ap0, bfrag[1][t][0], acc[t], 0, 0, 0);
        acc[t] = __builtin_amdgcn_mfma_f32_16x16x32_bf16(ap1, bfrag[1][t][1], acc[t], 0, 0, 0);
    }

    // epilogue: C/D layout col=lane&15, row=quad*4+reg (m89-verified)
    float m = 0.f;
#pragma unroll
    for (int t = 0; t < 4; ++t)
#pragma unroll
        for (int i = 0; i < 4; ++i) {
            float v = acc[t][i];
            float o = v > 0.f ? v : 0.2f * v;
            m = fmaxf(m, fabsf(o));
            ego_h[(size_t)(r0 + quad * 4 + i) * EMB + t * 16 + n] = f2bf(o);
        }
#pragma unroll
    for (int off = 1; off < 64; off <<= 1) m = fmaxf(m, __shfl_xor(m, off));
    if (lane == 0) smax[wave] = m;
    __syncthreads();
    if (threadIdx.x == 0)
        partial[blockIdx.x] = fmaxf(fmaxf(smax[0], smax[1]), fmaxf(smax[2], smax[3]));
}

// gather batch rows of ego_h (bf16), L2-normalize, write out cols [64*layer,...)
__global__ void gather_norm(const int* __restrict__ users, const int* __restrict__ pos,
                            const int* __restrict__ neg,
                            const unsigned short* __restrict__ ego_h,
                            float* __restrict__ out, int layer) {
    int b = blockIdx.x;
    int lane = threadIdx.x;
    int node = batch_node(users, pos, neg, b);
    float v = bf2f(ego_h[(size_t)node * EMB + lane]);
    float s = v * v;
#pragma unroll
    for (int off = 32; off > 0; off >>= 1) s += __shfl_xor(s, off);
    float n = fmaxf(sqrtf(s), 1e-12f);
    out[(size_t)b * 256 + layer * EMB + lane] = v / n;
}

extern "C" void kernel_launch(void* const* d_in, const int* in_sizes, int n_in,
                              void* d_out, int out_size, void* d_ws, size_t ws_size,
                              hipStream_t stream) {
    const int*   users    = (const int*)d_in[0];
    const int*   pos      = (const int*)d_in[1];
    const int*   neg      = (const int*)d_in[2];
    const int*   adj_row  = (const int*)d_in[3];
    const int*   adj_col  = (const int*)d_in[4];
    const float* adj_val  = (const float*)d_in[5];
    const float* user_emb = (const float*)d_in[6];
    const float* item_emb = (const float*)d_in[7];
    // d_in[8..19]: W_gc_0, b_gc_0, W_bi_0, b_bi_0, W_gc_1, ... (4 per layer)

    unsigned short* ego_h   = (unsigned short*)d_ws;
    unsigned short* side_h  = ego_h + (size_t)N_NODES * EMB;
    unsigned char*  ego_q   = (unsigned char*)(side_h + (size_t)N_NODES * EMB);
    float*          gmax    = (float*)(ego_q + (size_t)N_NODES * EMB);
    float*          partial = gmax + 4;
    int*            row_ptr = (int*)(partial + 50000);
    unsigned short* wfrag   = (unsigned short*)(row_ptr + 200704 + 28);  // 16B-aligned
    float*          out     = (float*)d_out;

    build_row_ptr<<<(NNZ + 255) / 256, 256, 0, stream>>>(adj_row, row_ptr);
    concat_ego<<<N_NODES / 4, 256, 0, stream>>>(user_emb, item_emb, ego_h, partial);
    reduce_max<<<1, 1024, 0, stream>>>(partial, N_NODES / 4, gmax);
    prep_wfrags<<<48, 64, 0, stream>>>((const float*)d_in[8], (const float*)d_in[10],
                                       (const float*)d_in[12], (const float*)d_in[14],
                                       (const float*)d_in[16], (const float*)d_in[18], wfrag);
    gather_layer0<<<3 * BATCH, 64, 0, stream>>>(users, pos, neg, user_emb, item_emb, out);
    quant_pass<<<(N_NODES * EMB / 8 + 255) / 256, 256, 0, stream>>>(ego_h, gmax, 0, ego_q);

    for (int k = 0; k < 3; ++k) {
        const float* bgc = (const float*)d_in[9 + 4 * k];
        const float* bbi = (const float*)d_in[11 + 4 * k];
        spmm_csr<<<N_NODES / 4, 256, 0, stream>>>(row_ptr, adj_col, adj_val, ego_q, gmax, k, side_h);
        dense_mfma<<<N_NODES / 64, 256, 0, stream>>>(side_h, ego_h,
                                                     wfrag + (size_t)k * 2 * 8 * 64 * 8,
                                                     bgc, bbi, partial);
        if (k < 2) {
            reduce_max<<<1, 1024, 0, stream>>>(partial, N_NODES / 64, gmax + k + 1);
            quant_pass<<<(N_NODES * EMB / 8 + 255) / 256, 256, 0, stream>>>(ego_h, gmax, k + 1, ego_q);
        }
        gather_norm<<<3 * BATCH, 64, 0, stream>>>(users, pos, neg, ego_h, out, k + 1);
    }
}

// Round 9
// 615.535 us; speedup vs baseline: 5.3085x; 1.0561x over previous
//
#include <hip/hip_runtime.h>

#define N_USER 100000
#define N_ITEM 100000
#define N_NODES 200000
#define NNZ 6400000
#define EMB 64
#define BATCH 1024

typedef __attribute__((ext_vector_type(8))) short bf16x8;   // 8 bf16 = 4 VGPRs
typedef __attribute__((ext_vector_type(4))) float f32x4;    // MFMA 16x16 acc

// ---------------------------------------------------------------------------
// Workspace layout:
//   ego_h   : N_NODES*EMB bf16  (25.6 MB) bf16 state (dense A-operand, gather_norm)
//   side_h  : N_NODES*EMB bf16  (25.6 MB) spmm output
//   ego_q   : N_NODES*EMB u8    (12.8 MB) offset-binary u8 state (spmm gather)
//   gmax    : 4 floats                    per-layer global absmax
//   partial : 50000 floats                block-level max partials (no atomics!)
//   row_ptr : padded ints                 CSR row starts (adj_row is sorted)
//   wfrag   : 6*8*64*8 bf16     (48 KB)   weights pre-packed into B-fragments
// R7 lesson: spmm was LATENCY/MLP-bound (VGPR=20 -> gathers serialized).
// R9: batch-issue all 8 gathers per 32-chunk before consuming (array state).
// ---------------------------------------------------------------------------

// f32 -> bf16 (RNE), raw ushort bits
__device__ __forceinline__ unsigned short f2bf(float f) {
    unsigned int b = __builtin_bit_cast(unsigned int, f);
    b += 0x7FFFu + ((b >> 16) & 1u);
    return (unsigned short)(b >> 16);
}
__device__ __forceinline__ float bf2f(unsigned short u) {
    return __builtin_bit_cast(float, (unsigned int)u << 16);
}
__device__ __forceinline__ unsigned int pack2(float lo, float hi) {
    return ((unsigned int)f2bf(hi) << 16) | f2bf(lo);
}
// offset-binary u8 quant: u = rint(v*inv)+128, inv = 127/gmax
__device__ __forceinline__ unsigned int quant_u8(float v, float inv) {
    return (unsigned int)((int)__builtin_rintf(v * inv) + 128);
}

// elementwise product of two bf16 fragments (A-layouts align), f32 math
__device__ __forceinline__ bf16x8 mul_bf(bf16x8 a, bf16x8 b) {
    bf16x8 r;
#pragma unroll
    for (int j = 0; j < 8; ++j) {
        float f = bf2f((unsigned short)a[j]) * bf2f((unsigned short)b[j]);
        r[j] = (short)f2bf(f);
    }
    return r;
}

// row_ptr[r] = lower_bound(adj_row, r); every r in [0, N_NODES] written once.
__global__ void build_row_ptr(const int* __restrict__ row, int* __restrict__ row_ptr) {
    int i = blockIdx.x * blockDim.x + threadIdx.x;
    if (i >= NNZ) return;
    int b = row[i];
    int a = (i == 0) ? -1 : row[i - 1];
    for (int r = a + 1; r <= b; ++r) row_ptr[r] = i;
    if (i == NNZ - 1) {
        for (int r = b + 1; r <= N_NODES; ++r) row_ptr[r] = NNZ;
    }
}

// wave per node row: bf16 state; block max -> partial[blockIdx] (no atomics)
__global__ __launch_bounds__(256) void concat_ego(
        const float* __restrict__ ue, const float* __restrict__ ie,
        unsigned short* __restrict__ ego_h, float* __restrict__ partial) {
    __shared__ float smax[4];
    int wave = (blockIdx.x * blockDim.x + threadIdx.x) >> 6;
    int lane = threadIdx.x & 63;
    float m = 0.f;
    if (wave < N_NODES) {
        float v = (wave < N_USER) ? ue[(size_t)wave * EMB + lane]
                                  : ie[(size_t)(wave - N_USER) * EMB + lane];
        ego_h[(size_t)wave * EMB + lane] = f2bf(v);
        m = fabsf(v);
    }
#pragma unroll
    for (int off = 1; off < 64; off <<= 1) m = fmaxf(m, __shfl_xor(m, off));
    if (lane == 0) smax[threadIdx.x >> 6] = m;
    __syncthreads();
    if (threadIdx.x == 0)
        partial[blockIdx.x] = fmaxf(fmaxf(smax[0], smax[1]), fmaxf(smax[2], smax[3]));
}

// fold partial[0..n) into gmax_out[0]; single block of 1024
__global__ __launch_bounds__(1024) void reduce_max(
        const float* __restrict__ partial, int n, float* __restrict__ gmax_out) {
    __shared__ float smax[16];
    float m = 0.f;
    for (int i = threadIdx.x; i < n; i += 1024) m = fmaxf(m, partial[i]);
#pragma unroll
    for (int off = 1; off < 64; off <<= 1) m = fmaxf(m, __shfl_xor(m, off));
    if ((threadIdx.x & 63) == 0) smax[threadIdx.x >> 6] = m;
    __syncthreads();
    if (threadIdx.x < 16) {
        m = smax[threadIdx.x];
#pragma unroll
        for (int off = 1; off < 16; off <<= 1) m = fmaxf(m, __shfl_xor(m, off));
        if (threadIdx.x == 0) gmax_out[0] = m;
    }
}

// streaming quant pass: ego_q = u8(ego_h) with global scale gmax[layer]
__global__ __launch_bounds__(256) void quant_pass(
        const unsigned short* __restrict__ ego_h, const float* __restrict__ gmax,
        int layer, unsigned char* __restrict__ ego_q) {
    int i = blockIdx.x * blockDim.x + threadIdx.x;   // 8-elem group index
    const int tot8 = N_NODES * EMB / 8;
    if (i >= tot8) return;
    float gm = gmax[layer];
    float inv = gm > 0.f ? 127.f / gm : 0.f;
    bf16x8 h = ((const bf16x8*)ego_h)[i];
    uint2 o;
    o.x = 0; o.y = 0;
#pragma unroll
    for (int j = 0; j < 4; ++j)
        o.x |= quant_u8(bf2f((unsigned short)h[j]), inv) << (8 * j);
#pragma unroll
    for (int j = 0; j < 4; ++j)
        o.y |= quant_u8(bf2f((unsigned short)h[4 + j]), inv) << (8 * j);
    ((uint2*)ego_q)[i] = o;
}

// pack the 6 64x64 f32 weight matrices into MFMA B-fragment layout (bf16).
__global__ void prep_wfrags(const float* __restrict__ W0, const float* __restrict__ W1,
                            const float* __restrict__ W2, const float* __restrict__ W3,
                            const float* __restrict__ W4, const float* __restrict__ W5,
                            unsigned short* __restrict__ wfrag) {
    int m = blockIdx.x >> 3;
    int t = (blockIdx.x >> 1) & 3, c = blockIdx.x & 1;
    const float* W = m == 0 ? W0 : m == 1 ? W1 : m == 2 ? W2 : m == 3 ? W3 : m == 4 ? W4 : W5;
    int l = threadIdx.x, quad = l >> 4, n = l & 15;
    unsigned short* dst = wfrag + ((size_t)blockIdx.x * 64 + l) * 8;
#pragma unroll
    for (int j = 0; j < 8; ++j)
        dst[j] = f2bf(W[(c * 32 + quad * 8 + j) * 64 + t * 16 + n]);
}

__device__ __forceinline__ int batch_node(const int* users, const int* pos,
                                          const int* neg, int b) {
    int t = b >> 10, idx = b & 1023;
    if (t == 0) return users[idx];
    if (t == 1) return N_USER + pos[idx];
    return N_USER + neg[idx];
}

// layer-0 output columns: exact f32 from the original input embeddings
__global__ void gather_layer0(const int* __restrict__ users, const int* __restrict__ pos,
                              const int* __restrict__ neg, const float* __restrict__ ue,
                              const float* __restrict__ ie, float* __restrict__ out) {
    int b = blockIdx.x;
    int node = batch_node(users, pos, neg, b);
    float v = (node < N_USER) ? ue[(size_t)node * EMB + threadIdx.x]
                              : ie[(size_t)(node - N_USER) * EMB + threadIdx.x];
    out[(size_t)b * 256 + threadIdx.x] = v;
}

// CSR SpMM, u8 quarter-wave gather, GLOBAL dequant scale. Wave = 1 row;
// 16 lanes x dword (4 u8 dims) cover the 64B row -> one gather serves 4 nnz.
// MLP fix (R9): per 32-chunk, ALL 8 bpermutes + ALL 8 gathers are issued
// before any fma consumes them (array state -> 8 loads in flight), and the
// early-exit break is gone (tail lanes carry val=0/col=0, harmless).
__global__ __launch_bounds__(256) void spmm_csr(
        const int* __restrict__ row_ptr, const int* __restrict__ col,
        const float* __restrict__ val, const unsigned char* __restrict__ xq,
        const float* __restrict__ gmax, int layer,
        unsigned short* __restrict__ yh) {
    int wave = (blockIdx.x * blockDim.x + threadIdx.x) >> 6;
    int lane = threadIdx.x & 63;
    if (wave >= N_NODES) return;
    int q = lane >> 4, p = lane & 15;
    int q4 = q << 2;
    unsigned pb = (unsigned)p * 4u;                 // byte offset in row
    int j0 = row_ptr[wave], j1 = row_ptr[wave + 1];
    float a0 = 0.f, a1 = 0.f, a2 = 0.f, a3 = 0.f, cs = 0.f;
    for (int j = j0; j < j1; j += 32) {
        int jl = j + (lane & 31);                   // lanes 32..63 duplicate 0..31
        bool ok = jl < j1;
        int   cc = ok ? __builtin_nontemporal_load(col + jl) : 0;
        float vr = ok ? __builtin_nontemporal_load(val + jl) : 0.f;
        int   vvi = __builtin_bit_cast(int, vr);
        float    vts[8];
        unsigned dd[8];
#pragma unroll
        for (int s = 0; s < 8; ++s) {               // nnz group s*4 .. s*4+3
            int ct = __builtin_amdgcn_ds_bpermute(s * 16 + q4, cc);
            vts[s] = __builtin_bit_cast(float,
                       __builtin_amdgcn_ds_bpermute(s * 16 + q4, vvi));
            dd[s] = *(const unsigned*)(xq + ((unsigned)ct * 64u + pb));
        }
#pragma unroll
        for (int s = 0; s < 8; ++s) {
            unsigned d = dd[s];
            float v = vts[s];
            a0 = fmaf(v, (float)(d & 0xffu), a0);
            a1 = fmaf(v, (float)((d >> 8) & 0xffu), a1);
            a2 = fmaf(v, (float)((d >> 16) & 0xffu), a2);
            a3 = fmaf(v, (float)(d >> 24), a3);
            cs += v;
        }
    }
    // combine the 4 quarter-partials (lane p keeps dims 4p..4p+3)
    a0 += __shfl_xor(a0, 16); a0 += __shfl_xor(a0, 32);
    a1 += __shfl_xor(a1, 16); a1 += __shfl_xor(a1, 32);
    a2 += __shfl_xor(a2, 16); a2 += __shfl_xor(a2, 32);
    a3 += __shfl_xor(a3, 16); a3 += __shfl_xor(a3, 32);
    cs += __shfl_xor(cs, 16); cs += __shfl_xor(cs, 32);
    if (q == 0) {
        float gsc = gmax[layer] * (1.f / 127.f);
        float c128 = 128.f * cs;
        uint2 o;
        o.x = pack2(gsc * (a0 - c128), gsc * (a1 - c128));
        o.y = pack2(gsc * (a2 - c128), gsc * (a3 - c128));
        ((uint2*)(yh + (size_t)wave * EMB))[p] = o;   // 16 lanes x 8B = full row
    }
}

// MFMA dense layer: ego_h <- bf16(leaky_relu(side@Wgc+bgc+(ego*side)@Wbi+bbi)).
// Epilogue: bf16 stores; block max -> partial[blockIdx] (no atomics).
__global__ __launch_bounds__(256) void dense_mfma(
        const unsigned short* __restrict__ side_h,
        unsigned short* __restrict__ ego_h,
        const unsigned short* __restrict__ wf,   // this layer: [m][t][c][lane][8]
        const float* __restrict__ bgc, const float* __restrict__ bbi,
        float* __restrict__ partial) {
    __shared__ float smax[4];
    int wave = threadIdx.x >> 6;
    int lane = threadIdx.x & 63;
    int quad = lane >> 4, n = lane & 15;
    int r0 = blockIdx.x * 64 + wave * 16;

    bf16x8 bfrag[2][4][2];
#pragma unroll
    for (int m = 0; m < 2; ++m)
#pragma unroll
        for (int t = 0; t < 4; ++t)
#pragma unroll
            for (int c = 0; c < 2; ++c)
                bfrag[m][t][c] = *(const bf16x8*)(wf + ((size_t)((m * 4 + t) * 2 + c) * 64 + lane) * 8);

    f32x4 acc[4];
#pragma unroll
    for (int t = 0; t < 4; ++t) {
        float bs = bgc[t * 16 + n] + bbi[t * 16 + n];
        acc[t] = (f32x4){bs, bs, bs, bs};
    }

    size_t abase = (size_t)(r0 + n) * EMB + quad * 8;
    bf16x8 as0 = *(const bf16x8*)(side_h + abase);
    bf16x8 as1 = *(const bf16x8*)(side_h + abase + 32);
    bf16x8 ae0 = *(const bf16x8*)(ego_h + abase);
    bf16x8 ae1 = *(const bf16x8*)(ego_h + abase + 32);
    bf16x8 ap0 = mul_bf(ae0, as0);
    bf16x8 ap1 = mul_bf(ae1, as1);

#pragma unroll
    for (int t = 0; t < 4; ++t) {
        acc[t] = __builtin_amdgcn_mfma_f32_16x16x32_bf16(as0, bfrag[0][t][0], acc[t], 0, 0, 0);
        acc[t] = __builtin_amdgcn_mfma_f32_16x16x32_bf16(as1, bfrag[0][t][1], acc[t], 0, 0, 0);
        acc[t] = __builtin_amdgcn_mfma_f32_16x16x32_bf16(ap0, bfrag[1][t][0], acc[t], 0, 0, 0);
        acc[t] = __builtin_amdgcn_mfma_f32_16x16x32_bf16(ap1, bfrag[1][t][1], acc[t], 0, 0, 0);
    }

    // epilogue: C/D layout col=lane&15, row=quad*4+reg (m89-verified)
    float m = 0.f;
#pragma unroll
    for (int t = 0; t < 4; ++t)
#pragma unroll
        for (int i = 0; i < 4; ++i) {
            float v = acc[t][i];
            float o = v > 0.f ? v : 0.2f * v;
            m = fmaxf(m, fabsf(o));
            ego_h[(size_t)(r0 + quad * 4 + i) * EMB + t * 16 + n] = f2bf(o);
        }
#pragma unroll
    for (int off = 1; off < 64; off <<= 1) m = fmaxf(m, __shfl_xor(m, off));
    if (lane == 0) smax[wave] = m;
    __syncthreads();
    if (threadIdx.x == 0)
        partial[blockIdx.x] = fmaxf(fmaxf(smax[0], smax[1]), fmaxf(smax[2], smax[3]));
}

// gather batch rows of ego_h (bf16), L2-normalize, write out cols [64*layer,...)
__global__ void gather_norm(const int* __restrict__ users, const int* __restrict__ pos,
                            const int* __restrict__ neg,
                            const unsigned short* __restrict__ ego_h,
                            float* __restrict__ out, int layer) {
    int b = blockIdx.x;
    int lane = threadIdx.x;
    int node = batch_node(users, pos, neg, b);
    float v = bf2f(ego_h[(size_t)node * EMB + lane]);
    float s = v * v;
#pragma unroll
    for (int off = 32; off > 0; off >>= 1) s += __shfl_xor(s, off);
    float n = fmaxf(sqrtf(s), 1e-12f);
    out[(size_t)b * 256 + layer * EMB + lane] = v / n;
}

extern "C" void kernel_launch(void* const* d_in, const int* in_sizes, int n_in,
                              void* d_out, int out_size, void* d_ws, size_t ws_size,
                              hipStream_t stream) {
    const int*   users    = (const int*)d_in[0];
    const int*   pos      = (const int*)d_in[1];
    const int*   neg      = (const int*)d_in[2];
    const int*   adj_row  = (const int*)d_in[3];
    const int*   adj_col  = (const int*)d_in[4];
    const float* adj_val  = (const float*)d_in[5];
    const float* user_emb = (const float*)d_in[6];
    const float* item_emb = (const float*)d_in[7];
    // d_in[8..19]: W_gc_0, b_gc_0, W_bi_0, b_bi_0, W_gc_1, ... (4 per layer)

    unsigned short* ego_h   = (unsigned short*)d_ws;
    unsigned short* side_h  = ego_h + (size_t)N_NODES * EMB;
    unsigned char*  ego_q   = (unsigned char*)(side_h + (size_t)N_NODES * EMB);
    float*          gmax    = (float*)(ego_q + (size_t)N_NODES * EMB);
    float*          partial = gmax + 4;
    int*            row_ptr = (int*)(partial + 50000);
    unsigned short* wfrag   = (unsigned short*)(row_ptr + 200704 + 28);  // 16B-aligned
    float*          out     = (float*)d_out;

    build_row_ptr<<<(NNZ + 255) / 256, 256, 0, stream>>>(adj_row, row_ptr);
    concat_ego<<<N_NODES / 4, 256, 0, stream>>>(user_emb, item_emb, ego_h, partial);
    reduce_max<<<1, 1024, 0, stream>>>(partial, N_NODES / 4, gmax);
    prep_wfrags<<<48, 64, 0, stream>>>((const float*)d_in[8], (const float*)d_in[10],
                                       (const float*)d_in[12], (const float*)d_in[14],
                                       (const float*)d_in[16], (const float*)d_in[18], wfrag);
    gather_layer0<<<3 * BATCH, 64, 0, stream>>>(users, pos, neg, user_emb, item_emb, out);
    quant_pass<<<(N_NODES * EMB / 8 + 255) / 256, 256, 0, stream>>>(ego_h, gmax, 0, ego_q);

    for (int k = 0; k < 3; ++k) {
        const float* bgc = (const float*)d_in[9 + 4 * k];
        const float* bbi = (const float*)d_in[11 + 4 * k];
        spmm_csr<<<N_NODES / 4, 256, 0, stream>>>(row_ptr, adj_col, adj_val, ego_q, gmax, k, side_h);
        dense_mfma<<<N_NODES / 64, 256, 0, stream>>>(side_h, ego_h,
                                                     wfrag + (size_t)k * 2 * 8 * 64 * 8,
                                                     bgc, bbi, partial);
        if (k < 2) {
            reduce_max<<<1, 1024, 0, stream>>>(partial, N_NODES / 64, gmax + k + 1);
            quant_pass<<<(N_NODES * EMB / 8 + 255) / 256, 256, 0, stream>>>(ego_h, gmax, k + 1, ego_q);
        }
        gather_norm<<<3 * BATCH, 64, 0, stream>>>(users, pos, neg, ego_h, out, k + 1);
    }
}